// Round 1
// baseline (7957.211 us; speedup 1.0000x reference)
//
#include <hip/hip_runtime.h>

#define B_  32
#define L_  2048
#define IN_ 512
#define H_  512
#define C_  1000

typedef __bf16 bf16x8 __attribute__((ext_vector_type(8)));
typedef short  short8 __attribute__((ext_vector_type(8)));
typedef float  floatx4 __attribute__((ext_vector_type(4)));

__device__ __forceinline__ unsigned short f2bf(float x) {
    unsigned u = __builtin_bit_cast(unsigned, x);
    unsigned r = (u + 0x7fffu + ((u >> 16) & 1u)) >> 16;
    return (unsigned short)r;
}
__device__ __forceinline__ float bf2f(unsigned short s) {
    unsigned u = ((unsigned)s) << 16;
    return __builtin_bit_cast(float, u);
}

// ---------------------------------------------------------------------------
// Generic C[M x Nreal] = A[M x 512] * W[Nreal x 512]^T + bias, fp32 in/out,
// bf16 MFMA compute. grid = (Ntiles, Mtiles), block = 256 (4 waves, 2x2).
// ---------------------------------------------------------------------------
__global__ __launch_bounds__(256) void gemm_bias(
    const float* __restrict__ A, const float* __restrict__ W,
    const float* __restrict__ bias, float* __restrict__ Cc,
    int ldc, int Nreal)
{
    __shared__ unsigned short As[128 * 40];   // [row][k], k-pad 32->40
    __shared__ unsigned short Bs[128 * 40];   // [nrow][k]

    const int tid  = threadIdx.x;
    const int lane = tid & 63;
    const int wv   = tid >> 6;       // 0..3
    const int wm   = wv >> 1;        // row half
    const int wn   = wv & 1;         // col half
    const int quad = lane >> 4;
    const long mbase = (long)blockIdx.y * 128;
    const int  nbase = blockIdx.x * 128;

    floatx4 acc[4][4];
#pragma unroll
    for (int mt = 0; mt < 4; ++mt)
#pragma unroll
        for (int nt = 0; nt < 4; ++nt)
            acc[mt][nt] = (floatx4){0.f, 0.f, 0.f, 0.f};

    for (int kt = 0; kt < 16; ++kt) {
        const int kbase = kt * 32;
        // stage A and B tiles: 128 rows x 32 cols fp32 -> bf16 LDS
#pragma unroll
        for (int i = 0; i < 4; ++i) {
            const int f  = tid + i * 256;       // 0..1023 float4 slots
            const int r  = f >> 3;              // 0..127
            const int c4 = f & 7;               // 0..7
            const float4 va = *(const float4*)(A + (mbase + r) * 512 + kbase + c4 * 4);
            unsigned alo = (unsigned)f2bf(va.x) | ((unsigned)f2bf(va.y) << 16);
            unsigned ahi = (unsigned)f2bf(va.z) | ((unsigned)f2bf(va.w) << 16);
            *(uint2*)(&As[r * 40 + c4 * 4]) = make_uint2(alo, ahi);

            const int n_g = nbase + r;
            float4 vb;
            if (n_g < Nreal) vb = *(const float4*)(W + (long)n_g * 512 + kbase + c4 * 4);
            else             vb = make_float4(0.f, 0.f, 0.f, 0.f);
            unsigned blo = (unsigned)f2bf(vb.x) | ((unsigned)f2bf(vb.y) << 16);
            unsigned bhi = (unsigned)f2bf(vb.z) | ((unsigned)f2bf(vb.w) << 16);
            *(uint2*)(&Bs[r * 40 + c4 * 4]) = make_uint2(blo, bhi);
        }
        __syncthreads();

        bf16x8 af[4], bfr[4];
#pragma unroll
        for (int mt = 0; mt < 4; ++mt)
            af[mt] = *(const bf16x8*)(&As[(wm * 64 + mt * 16 + (lane & 15)) * 40 + quad * 8]);
#pragma unroll
        for (int nt = 0; nt < 4; ++nt)
            bfr[nt] = *(const bf16x8*)(&Bs[(wn * 64 + nt * 16 + (lane & 15)) * 40 + quad * 8]);
#pragma unroll
        for (int mt = 0; mt < 4; ++mt)
#pragma unroll
            for (int nt = 0; nt < 4; ++nt)
                acc[mt][nt] = __builtin_amdgcn_mfma_f32_16x16x32_bf16(
                    af[mt], bfr[nt], acc[mt][nt], 0, 0, 0);
        __syncthreads();
    }

    // epilogue: D row=(lane>>4)*4+i, col=lane&15
#pragma unroll
    for (int nt = 0; nt < 4; ++nt) {
        const int col = nbase + wn * 64 + nt * 16 + (lane & 15);
        if (col < Nreal) {
            const float bv = bias[col];
#pragma unroll
            for (int mt = 0; mt < 4; ++mt) {
#pragma unroll
                for (int i = 0; i < 4; ++i) {
                    const long row = mbase + wm * 64 + mt * 16 + quad * 4 + i;
                    Cc[row * (long)ldc + col] = acc[mt][nt][i] + bv;
                }
            }
        }
    }
}

// ---------------------------------------------------------------------------
// Recurrence: 64 WGs x 256 threads. WG = (group=wg>>3 -> 4 batches,
// slice=wg&7 -> 64 output rows). Wh slice lives in VGPRs as B-fragments
// (16 frags/wave, loaded once). h exchanged per step via IF-coherent
// (agent-scope relaxed atomic, sc1) double buffer in d_ws + flags.
// A-operand = h split hi/lo bf16 for fp32-grade accuracy.
// ---------------------------------------------------------------------------
__global__ __launch_bounds__(256, 1) void rnn_scan(
    const float* __restrict__ Wh, const float* __restrict__ bh,
    const float* __restrict__ hidden, const float* __restrict__ xp,
    float* __restrict__ hn, unsigned int* ws)
{
    __shared__ unsigned short lds_hi[5 * 520];  // rows 0-3 = h, row 4 = zeros
    __shared__ unsigned short lds_lo[5 * 520];

    const int tid   = threadIdx.x;
    const int lane  = tid & 63;
    const int wv    = tid >> 6;        // wave = ntile 0..3
    const int wg    = blockIdx.x;      // 0..63
    const int group = wg >> 3;         // 0..7
    const int slice = wg & 7;          // 0..7
    const int b0    = group * 4;
    const int n0    = slice * 64;
    const int quad  = lane >> 4;
    const int rr    = ((lane & 15) < 4) ? (lane & 15) : 4;   // A row (zero-pad)

    unsigned int* flags = ws;                       // 64 entries
    float* exch = (float*)(ws + 1024);              // [8][2][4][512] fp32

    // ---- load Wh B-fragments once (bf16, in VGPRs) ----
    bf16x8 wf[16];
    {
        const int n_row = n0 + wv * 16 + (lane & 15);
#pragma unroll
        for (int kk = 0; kk < 16; ++kk) {
            const float4 w0 = *(const float4*)(Wh + (long)n_row * 512 + kk * 32 + quad * 8);
            const float4 w1 = *(const float4*)(Wh + (long)n_row * 512 + kk * 32 + quad * 8 + 4);
            short8 s;
            s[0] = (short)f2bf(w0.x); s[1] = (short)f2bf(w0.y);
            s[2] = (short)f2bf(w0.z); s[3] = (short)f2bf(w0.w);
            s[4] = (short)f2bf(w1.x); s[5] = (short)f2bf(w1.y);
            s[6] = (short)f2bf(w1.z); s[7] = (short)f2bf(w1.w);
            wf[kk] = __builtin_bit_cast(bf16x8, s);
        }
    }

    const int   n_lane = n0 + wv * 16 + (lane & 15);   // output col this lane handles
    const int   b_lane = b0 + quad;                    // batch this lane handles
    const float bias_v = bh[n_lane];

    // ---- initial stage: zero pad row, h0 from hidden[:,0,:] ----
    for (int i = tid; i < 520; i += 256) { lds_hi[4 * 520 + i] = 0; lds_lo[4 * 520 + i] = 0; }
#pragma unroll
    for (int i = 0; i < 8; ++i) {
        const int idx = tid + i * 256;          // 0..2047
        const int r = idx >> 9, c = idx & 511;
        const float v = hidden[((long)(b0 + r) * L_) * H_ + c];
        const unsigned short hv = f2bf(v);
        lds_hi[r * 520 + c] = hv;
        lds_lo[r * 520 + c] = f2bf(v - bf2f(hv));
    }
    __syncthreads();

    for (int t = 0; t < L_; ++t) {
        // xp for this step (plain load, issued early, latency hidden)
        const float xpv = xp[((long)b_lane * L_ + t) * H_ + n_lane];

        if (t > 0) {
            // ---- wait for all 8 slices of h_t ----
            const unsigned tu = (unsigned)t;
            for (;;) {
                int ok = 1;
                if (lane < 8) {
                    unsigned f = __hip_atomic_load(&flags[group * 8 + lane],
                                                   __ATOMIC_RELAXED, __HIP_MEMORY_SCOPE_AGENT);
                    ok = (f >= tu);
                }
                if (__all(ok)) break;
            }
            asm volatile("" ::: "memory");  // keep data loads after poll

            // ---- read h_t (4x512 fp32) from IF, split hi/lo into LDS ----
            const unsigned long long* src =
                (const unsigned long long*)(exch + (size_t)((group * 2 + (t & 1)) * 4) * 512);
            unsigned long long uv[4];
#pragma unroll
            for (int i = 0; i < 4; ++i)
                uv[i] = __hip_atomic_load((unsigned long long*)(src + tid + i * 256),
                                          __ATOMIC_RELAXED, __HIP_MEMORY_SCOPE_AGENT);
#pragma unroll
            for (int i = 0; i < 4; ++i) {
                const int p = tid + i * 256;      // u64 index 0..1023
                const int e = 2 * p;
                const int r = e >> 9, c = e & 511;
                const float v0 = __builtin_bit_cast(float, (unsigned)(uv[i] & 0xffffffffu));
                const float v1 = __builtin_bit_cast(float, (unsigned)(uv[i] >> 32));
                const unsigned short h0v = f2bf(v0);
                const unsigned short h1v = f2bf(v1);
                const int o = r * 520 + c;
                lds_hi[o]     = h0v;               lds_hi[o + 1] = h1v;
                lds_lo[o]     = f2bf(v0 - bf2f(h0v));
                lds_lo[o + 1] = f2bf(v1 - bf2f(h1v));
            }
        }
        __syncthreads();   // staging visible to all waves

        // ---- MFMA: D[0..3][n0+wv*16 .. +15] over K=512, hi+lo chains ----
        floatx4 a0 = (floatx4){0.f, 0.f, 0.f, 0.f};
        floatx4 a1 = (floatx4){0.f, 0.f, 0.f, 0.f};
#pragma unroll
        for (int kk = 0; kk < 16; ++kk) {
            const bf16x8 ah = *(const bf16x8*)(&lds_hi[rr * 520 + kk * 32 + quad * 8]);
            const bf16x8 al = *(const bf16x8*)(&lds_lo[rr * 520 + kk * 32 + quad * 8]);
            a0 = __builtin_amdgcn_mfma_f32_16x16x32_bf16(ah, wf[kk], a0, 0, 0, 0);
            a1 = __builtin_amdgcn_mfma_f32_16x16x32_bf16(al, wf[kk], a1, 0, 0, 0);
        }
        __syncthreads();   // all LDS frag reads done -> next staging is safe

        // ---- epilogue: spread D (lives in lanes 0-15, regs 0-3) to 64 lanes ----
        const float c0 = a0[0] + a1[0], c1 = a0[1] + a1[1];
        const float c2 = a0[2] + a1[2], c3 = a0[3] + a1[3];
        const int srcl = lane & 15;
        const float s0 = __shfl(c0, srcl);
        const float s1 = __shfl(c1, srcl);
        const float s2 = __shfl(c2, srcl);
        const float s3 = __shfl(c3, srcl);
        float pre = (quad == 0) ? s0 : ((quad == 1) ? s1 : ((quad == 2) ? s2 : s3));
        pre += xpv + bias_v;
        const float e2 = __expf(pre + pre);
        const float hval = 1.0f - 2.0f / (e2 + 1.0f);   // tanh(pre)

        // publish slice of h_{t+1} (write-through to IF)
        {
            unsigned int* dst =
                (unsigned int*)(exch + (size_t)(((group * 2 + ((t + 1) & 1)) * 4 + quad)) * 512);
            __hip_atomic_store(dst + n_lane, __builtin_bit_cast(unsigned, hval),
                               __ATOMIC_RELAXED, __HIP_MEMORY_SCOPE_AGENT);
        }
        asm volatile("s_waitcnt vmcnt(0)" ::: "memory");  // drain before flag
        __syncthreads();                                  // all waves drained
        if (tid == 0)
            __hip_atomic_store(&flags[wg], (unsigned)(t + 1),
                               __ATOMIC_RELAXED, __HIP_MEMORY_SCOPE_AGENT);

        // h_n output store (off critical path: after flag; drained next step)
        hn[((long)b_lane * L_ + t) * H_ + n_lane] = hval;
    }
}

// ---------------------------------------------------------------------------
extern "C" void kernel_launch(void* const* d_in, const int* in_sizes, int n_in,
                              void* d_out, int out_size, void* d_ws, size_t ws_size,
                              hipStream_t stream)
{
    const float* inputs = (const float*)d_in[0];
    const float* hidden = (const float*)d_in[1];
    const float* Wi     = (const float*)d_in[2];
    const float* bi     = (const float*)d_in[3];
    const float* Wh     = (const float*)d_in[4];
    const float* bh     = (const float*)d_in[5];
    const float* Wo     = (const float*)d_in[6];
    const float* bo     = (const float*)d_in[7];

    float* out = (float*)d_out;
    float* xp  = out;                                   // scratch: overwritten by phase 3
    float* hn  = out + (long)B_ * L_ * C_;              // h_n output region

    // zero the sync flags (d_ws is re-poisoned to 0xAA before every launch)
    hipMemsetAsync(d_ws, 0, 4096, stream);

    // Phase 1: x_proj = inputs * Wi^T + bi   -> xp [65536 x 512]
    gemm_bias<<<dim3(4, 512), 256, 0, stream>>>(inputs, Wi, bi, xp, 512, 512);

    // Phase 2: sequential recurrence -> hn [32 x 2048 x 512]
    rnn_scan<<<dim3(64), 256, 0, stream>>>(Wh, bh, hidden, xp, hn, (unsigned int*)d_ws);

    // Phase 3: output = h_n * Wo^T + bo -> out [65536 x 1000] (overwrites xp)
    gemm_bias<<<dim3(8, 512), 256, 0, stream>>>(hn, Wo, bo, out, 1000, 1000);
}

// Round 2
// 5698.723 us; speedup vs baseline: 1.3963x; 1.3963x over previous
//
#include <hip/hip_runtime.h>

#define B_  32
#define L_  2048
#define IN_ 512
#define H_  512
#define C_  1000

typedef __bf16 bf16x8 __attribute__((ext_vector_type(8)));
typedef short  short8 __attribute__((ext_vector_type(8)));
typedef float  floatx4 __attribute__((ext_vector_type(4)));

__device__ __forceinline__ unsigned short f2bf(float x) {
    unsigned u = __builtin_bit_cast(unsigned, x);
    unsigned r = (u + 0x7fffu + ((u >> 16) & 1u)) >> 16;
    return (unsigned short)r;
}
__device__ __forceinline__ float bf2f(unsigned short s) {
    unsigned u = ((unsigned)s) << 16;
    return __builtin_bit_cast(float, u);
}

// ---------------------------------------------------------------------------
// Generic C[M x Nreal] = A[M x 512] * W[Nreal x 512]^T + bias, fp32 in/out,
// bf16 MFMA compute. grid = (Ntiles, Mtiles), block = 256 (4 waves, 2x2).
// ---------------------------------------------------------------------------
__global__ __launch_bounds__(256) void gemm_bias(
    const float* __restrict__ A, const float* __restrict__ W,
    const float* __restrict__ bias, float* __restrict__ Cc,
    int ldc, int Nreal)
{
    __shared__ unsigned short As[128 * 40];   // [row][k], k-pad 32->40
    __shared__ unsigned short Bs[128 * 40];   // [nrow][k]

    const int tid  = threadIdx.x;
    const int lane = tid & 63;
    const int wv   = tid >> 6;       // 0..3
    const int wm   = wv >> 1;        // row half
    const int wn   = wv & 1;         // col half
    const int quad = lane >> 4;
    const long mbase = (long)blockIdx.y * 128;
    const int  nbase = blockIdx.x * 128;

    floatx4 acc[4][4];
#pragma unroll
    for (int mt = 0; mt < 4; ++mt)
#pragma unroll
        for (int nt = 0; nt < 4; ++nt)
            acc[mt][nt] = (floatx4){0.f, 0.f, 0.f, 0.f};

    for (int kt = 0; kt < 16; ++kt) {
        const int kbase = kt * 32;
#pragma unroll
        for (int i = 0; i < 4; ++i) {
            const int f  = tid + i * 256;       // 0..1023 float4 slots
            const int r  = f >> 3;              // 0..127
            const int c4 = f & 7;               // 0..7
            const float4 va = *(const float4*)(A + (mbase + r) * 512 + kbase + c4 * 4);
            unsigned alo = (unsigned)f2bf(va.x) | ((unsigned)f2bf(va.y) << 16);
            unsigned ahi = (unsigned)f2bf(va.z) | ((unsigned)f2bf(va.w) << 16);
            *(uint2*)(&As[r * 40 + c4 * 4]) = make_uint2(alo, ahi);

            const int n_g = nbase + r;
            float4 vb;
            if (n_g < Nreal) vb = *(const float4*)(W + (long)n_g * 512 + kbase + c4 * 4);
            else             vb = make_float4(0.f, 0.f, 0.f, 0.f);
            unsigned blo = (unsigned)f2bf(vb.x) | ((unsigned)f2bf(vb.y) << 16);
            unsigned bhi = (unsigned)f2bf(vb.z) | ((unsigned)f2bf(vb.w) << 16);
            *(uint2*)(&Bs[r * 40 + c4 * 4]) = make_uint2(blo, bhi);
        }
        __syncthreads();

        bf16x8 af[4], bfr[4];
#pragma unroll
        for (int mt = 0; mt < 4; ++mt)
            af[mt] = *(const bf16x8*)(&As[(wm * 64 + mt * 16 + (lane & 15)) * 40 + quad * 8]);
#pragma unroll
        for (int nt = 0; nt < 4; ++nt)
            bfr[nt] = *(const bf16x8*)(&Bs[(wn * 64 + nt * 16 + (lane & 15)) * 40 + quad * 8]);
#pragma unroll
        for (int mt = 0; mt < 4; ++mt)
#pragma unroll
            for (int nt = 0; nt < 4; ++nt)
                acc[mt][nt] = __builtin_amdgcn_mfma_f32_16x16x32_bf16(
                    af[mt], bfr[nt], acc[mt][nt], 0, 0, 0);
        __syncthreads();
    }

#pragma unroll
    for (int nt = 0; nt < 4; ++nt) {
        const int col = nbase + wn * 64 + nt * 16 + (lane & 15);
        if (col < Nreal) {
            const float bv = bias[col];
#pragma unroll
            for (int mt = 0; mt < 4; ++mt) {
#pragma unroll
                for (int i = 0; i < 4; ++i) {
                    const long row = mbase + wm * 64 + mt * 16 + quad * 4 + i;
                    Cc[row * (long)ldc + col] = acc[mt][nt][i] + bv;
                }
            }
        }
    }
}

// ---------------------------------------------------------------------------
// Recurrence: 64 WGs x 256 threads. group = wg>>3 (4 batches), slice = wg&7
// (64 output rows). Wh slice lives in VGPRs as B-fragments. h exchanged per
// step via TAGGED lock-free u64 slots ((tag<<32)|value) in an IF-resident
// double buffer: no flags, no producer drain, poll IS the data load.
// 2-buffer parity is skew-safe: publish(t+1) transitively requires all peers
// to have consumed t-1, so the slot overwritten (tag t-1) is dead.
// ---------------------------------------------------------------------------
__global__ __launch_bounds__(256, 1) void rnn_scan(
    const float* __restrict__ Wh, const float* __restrict__ bh,
    const float* __restrict__ hidden, const float* __restrict__ xp,
    float* __restrict__ hn, unsigned long long* exch)
{
    __shared__ unsigned short lds_hi[5 * 520];  // rows 0-3 = h, row 4 = zeros
    __shared__ unsigned short lds_lo[5 * 520];

    const int tid   = threadIdx.x;
    const int lane  = tid & 63;
    const int wv    = tid >> 6;        // wave = ntile 0..3
    const int wg    = blockIdx.x;      // 0..63
    const int group = wg >> 3;         // 0..7
    const int slice = wg & 7;          // 0..7
    const int b0    = group * 4;
    const int n0    = slice * 64;
    const int quad  = lane >> 4;
    const int rr    = ((lane & 15) < 4) ? (lane & 15) : 4;   // A row (zero-pad)

    // exch layout: [group 8][parity 2][elem 2048] u64; elem = batch*512 + col

    // ---- load Wh B-fragments once (bf16, in VGPRs) ----
    bf16x8 wf[16];
    {
        const int n_row = n0 + wv * 16 + (lane & 15);
#pragma unroll
        for (int kk = 0; kk < 16; ++kk) {
            const float4 w0 = *(const float4*)(Wh + (long)n_row * 512 + kk * 32 + quad * 8);
            const float4 w1 = *(const float4*)(Wh + (long)n_row * 512 + kk * 32 + quad * 8 + 4);
            short8 s;
            s[0] = (short)f2bf(w0.x); s[1] = (short)f2bf(w0.y);
            s[2] = (short)f2bf(w0.z); s[3] = (short)f2bf(w0.w);
            s[4] = (short)f2bf(w1.x); s[5] = (short)f2bf(w1.y);
            s[6] = (short)f2bf(w1.z); s[7] = (short)f2bf(w1.w);
            wf[kk] = __builtin_bit_cast(bf16x8, s);
        }
    }

    const int   n_lane = n0 + wv * 16 + (lane & 15);   // output col this lane handles
    const int   b_lane = b0 + quad;                    // batch this lane handles
    const float bias_v = bh[n_lane];

    // ---- initial stage: zero pad row, h0 from hidden[:,0,:] ----
    for (int i = tid; i < 520; i += 256) { lds_hi[4 * 520 + i] = 0; lds_lo[4 * 520 + i] = 0; }
#pragma unroll
    for (int i = 0; i < 8; ++i) {
        const int idx = tid + i * 256;          // 0..2047
        const int r = idx >> 9, c = idx & 511;
        const float v = hidden[((long)(b0 + r) * L_) * H_ + c];
        const unsigned short hv = f2bf(v);
        lds_hi[r * 520 + c] = hv;
        lds_lo[r * 520 + c] = f2bf(v - bf2f(hv));
    }
    __syncthreads();

    for (int t = 0; t < L_; ++t) {
        // xp for this step (issued early; arrives during poll/MFMA)
        const float xpv = xp[((long)b_lane * L_ + t) * H_ + n_lane];

        if (t > 0) {
            const unsigned tu = (unsigned)t;
            unsigned long long* src = exch + (size_t)(group * 2 + (t & 1)) * 2048;
            unsigned long long uv[8];
            unsigned pending = 0xffu;
            while (pending) {
#pragma unroll
                for (int i = 0; i < 8; ++i)
                    if (pending & (1u << i))
                        uv[i] = __hip_atomic_load(src + tid + i * 256,
                                                  __ATOMIC_RELAXED, __HIP_MEMORY_SCOPE_AGENT);
#pragma unroll
                for (int i = 0; i < 8; ++i)
                    if ((pending & (1u << i)) && (unsigned)(uv[i] >> 32) == tu)
                        pending &= ~(1u << i);
            }
            // stage fresh h_t into LDS hi/lo
#pragma unroll
            for (int i = 0; i < 8; ++i) {
                const int idx = tid + i * 256;
                const int r = idx >> 9, c = idx & 511;
                const float v = __builtin_bit_cast(float, (unsigned)(uv[i] & 0xffffffffu));
                const unsigned short hv = f2bf(v);
                lds_hi[r * 520 + c] = hv;
                lds_lo[r * 520 + c] = f2bf(v - bf2f(hv));
            }
        }
        __syncthreads();   // staging visible to all waves

        // ---- MFMA: D[0..3][n0+wv*16 .. +15] over K=512, hi+lo chains ----
        floatx4 a0 = (floatx4){0.f, 0.f, 0.f, 0.f};
        floatx4 a1 = (floatx4){0.f, 0.f, 0.f, 0.f};
#pragma unroll
        for (int kk = 0; kk < 16; ++kk) {
            const bf16x8 ah = *(const bf16x8*)(&lds_hi[rr * 520 + kk * 32 + quad * 8]);
            const bf16x8 al = *(const bf16x8*)(&lds_lo[rr * 520 + kk * 32 + quad * 8]);
            a0 = __builtin_amdgcn_mfma_f32_16x16x32_bf16(ah, wf[kk], a0, 0, 0, 0);
            a1 = __builtin_amdgcn_mfma_f32_16x16x32_bf16(al, wf[kk], a1, 0, 0, 0);
        }
        __syncthreads();   // all LDS frag reads done -> next staging is safe

        // ---- epilogue: spread D (lanes 0-15, regs 0-3) to 64 lanes ----
        const float c0 = a0[0] + a1[0], c1 = a0[1] + a1[1];
        const float c2 = a0[2] + a1[2], c3 = a0[3] + a1[3];
        const int srcl = lane & 15;
        const float s0 = __shfl(c0, srcl);
        const float s1 = __shfl(c1, srcl);
        const float s2 = __shfl(c2, srcl);
        const float s3 = __shfl(c3, srcl);
        float pre = (quad == 0) ? s0 : ((quad == 1) ? s1 : ((quad == 2) ? s2 : s3));
        pre += xpv + bias_v;
        const float e2 = __expf(pre + pre);
        const float hval = 1.0f - 2.0f / (e2 + 1.0f);   // tanh(pre)

        // publish slice of h_{t+1}: single atomic u64 = (tag<<32)|value.
        // No drain, no flag -- the tag rides with the data.
        {
            unsigned long long* dst = exch + (size_t)(group * 2 + ((t + 1) & 1)) * 2048
                                    + (size_t)quad * 512 + n_lane;
            const unsigned long long pk =
                ((unsigned long long)(unsigned)(t + 1) << 32) |
                (unsigned long long)__builtin_bit_cast(unsigned, hval);
            __hip_atomic_store(dst, pk, __ATOMIC_RELAXED, __HIP_MEMORY_SCOPE_AGENT);
        }

        // h_n output store (fire-and-forget, off critical path)
        hn[((long)b_lane * L_ + t) * H_ + n_lane] = hval;
    }
}

// ---------------------------------------------------------------------------
extern "C" void kernel_launch(void* const* d_in, const int* in_sizes, int n_in,
                              void* d_out, int out_size, void* d_ws, size_t ws_size,
                              hipStream_t stream)
{
    const float* inputs = (const float*)d_in[0];
    const float* hidden = (const float*)d_in[1];
    const float* Wi     = (const float*)d_in[2];
    const float* bi     = (const float*)d_in[3];
    const float* Wh     = (const float*)d_in[4];
    const float* bh     = (const float*)d_in[5];
    const float* Wo     = (const float*)d_in[6];
    const float* bo     = (const float*)d_in[7];

    float* out = (float*)d_out;
    float* xp  = out;                                   // scratch: overwritten by phase 3
    float* hn  = out + (long)B_ * L_ * C_;              // h_n output region

    // clear exchange tags (0xAA poison never matches, but first call is belt+braces)
    hipMemsetAsync(d_ws, 0, (size_t)8 * 2 * 2048 * 8, stream);

    // Phase 1: x_proj = inputs * Wi^T + bi   -> xp [65536 x 512]
    gemm_bias<<<dim3(4, 512), 256, 0, stream>>>(inputs, Wi, bi, xp, 512, 512);

    // Phase 2: sequential recurrence -> hn [32 x 2048 x 512]
    rnn_scan<<<dim3(64), 256, 0, stream>>>(Wh, bh, hidden, xp, hn,
                                           (unsigned long long*)d_ws);

    // Phase 3: output = h_n * Wo^T + bo -> out [65536 x 1000] (overwrites xp)
    gemm_bias<<<dim3(8, 512), 256, 0, stream>>>(hn, Wo, bo, out, 1000, 1000);
}